// Round 1
// baseline (331.038 us; speedup 1.0000x reference)
//
#include <hip/hip_runtime.h>

// SpatialAttention: B=4, HW=4096, C=256, NH=4, d=64.
// Flash-attention with f16 MFMA 16x16x32. fp32 in/out.
// Layouts (gfx950, verified per guide m89/m91/m120):
//   A-frag: A[m=lane&15][k=(lane>>4)*8+j]
//   B-frag: B[k=(lane>>4)*8+j][n=lane&15]
//   C/D   : D[row=(lane>>4)*4+reg][col=lane&15]

#define HW 4096
#define CCH 256
#define DH 64
#define NH 4
#define QTILE 128   // Q rows per block (8 waves x 16 rows)
#define KTILE 64    // keys per KV iteration
#define KS_STRIDE 72   // halves; 144B rows, 16B aligned, bank-balanced b128 reads
#define VT_STRIDE 76   // halves; 152B rows, 8B aligned, bank-balanced b64 r/w
#define P_STRIDE  72

typedef __attribute__((ext_vector_type(8))) _Float16 half8;
typedef __attribute__((ext_vector_type(4))) _Float16 half4;
typedef __attribute__((ext_vector_type(4))) float floatx4;

#define LOG2E 1.44269504088896340736f

__launch_bounds__(512, 1)
__global__ void spatial_attn_kernel(
    const float* __restrict__ q_in, const float* __restrict__ k_in,
    const float* __restrict__ v_in,
    const float* __restrict__ wq, const float* __restrict__ bq,
    const float* __restrict__ wk, const float* __restrict__ bk,
    const float* __restrict__ wv, const float* __restrict__ bv,
    const float* __restrict__ wp, const float* __restrict__ bp,
    float* __restrict__ out)
{
    __shared__ alignas(16) _Float16 Ks[KTILE * KS_STRIDE];   // [key][ch]
    __shared__ alignas(16) _Float16 Vt[DH * VT_STRIDE];      // [ch][key] (transposed)
    __shared__ alignas(16) _Float16 Ps[8 * 16 * P_STRIDE];   // per-wave P scratch

    const int tid  = threadIdx.x;
    const int wave = tid >> 6;
    const int lane = tid & 63;
    const int l15  = lane & 15;
    const int quad = lane >> 4;

    const int qtile = blockIdx.x;
    const int bh    = blockIdx.y;
    const int b     = bh >> 2;
    const int h     = bh & 3;
    const int ch0   = h * DH;

    // ---- Q fragments (A-layout), fold (wq,bq) and scale*log2e into q ----
    const int qrow = qtile * QTILE + wave * 16 + l15;
    const float qsc = 0.125f * LOG2E;   // d^-0.5 = 1/8, exp2-based softmax
    half8 qfrag[2];
    {
        const float* qp = q_in + ((size_t)b * HW + qrow) * CCH + ch0;
        #pragma unroll
        for (int c = 0; c < 2; ++c) {
            int k0 = c * 32 + quad * 8;
            #pragma unroll
            for (int j = 0; j < 8; ++j) {
                float v = qp[k0 + j] * wq[ch0 + k0 + j] + bq[ch0 + k0 + j];
                qfrag[c][j] = (_Float16)(v * qsc);
            }
        }
    }

    // ---- staging weight preloads (per-thread-constant channels) ----
    const int kch4 = (tid & 15) * 4;       // K staging: float4 of channels
    floatx4 wk4 = *(const floatx4*)(wk + ch0 + kch4);
    floatx4 bk4 = *(const floatx4*)(bk + ch0 + kch4);
    const int vch = tid & 63;              // V staging: one channel per thread
    const float wv_s = wv[ch0 + vch];
    const float bv_s = bv[ch0 + vch];

    floatx4 acc[4];
    float m_i[4], l_i[4];
    #pragma unroll
    for (int r = 0; r < 4; ++r) { m_i[r] = -1e30f; l_i[r] = 0.0f; }
    #pragma unroll
    for (int nt = 0; nt < 4; ++nt) {
        floatx4 z = {0.f, 0.f, 0.f, 0.f};
        acc[nt] = z;
    }

    _Float16* myP = Ps + wave * 16 * P_STRIDE;

    for (int kt = 0; kt < HW / KTILE; ++kt) {
        const int key0 = kt * KTILE;

        // ---- stage K tile: [key][ch], f32 -> f16 with (wk,bk) ----
        #pragma unroll
        for (int p = 0; p < 2; ++p) {
            int idx = tid + p * 512;
            int key = idx >> 4;
            const float* kp = k_in + ((size_t)b * HW + key0 + key) * CCH + ch0 + kch4;
            floatx4 kf = *(const floatx4*)kp;
            half4 kh;
            kh[0] = (_Float16)(kf.x * wk4.x + bk4.x);
            kh[1] = (_Float16)(kf.y * wk4.y + bk4.y);
            kh[2] = (_Float16)(kf.z * wk4.z + bk4.z);
            kh[3] = (_Float16)(kf.w * wk4.w + bk4.w);
            *(half4*)(&Ks[key * KS_STRIDE + kch4]) = kh;
        }

        // ---- stage V tile transposed: Vt[ch][key], f32 -> f16 with (wv,bv) ----
        #pragma unroll
        for (int p = 0; p < 2; ++p) {
            int g = tid + p * 512;
            int keyb = (g >> 6) * 4;
            const float* vp = v_in + ((size_t)b * HW + key0 + keyb) * CCH + ch0 + vch;
            half4 vh;
            #pragma unroll
            for (int j = 0; j < 4; ++j) {
                float vv = vp[j * CCH];
                vh[j] = (_Float16)(vv * wv_s + bv_s);
            }
            *(half4*)(&Vt[vch * VT_STRIDE + keyb]) = vh;
        }
        __syncthreads();

        // ---- S = q̂ · K^T  (16 rows x 64 keys per wave) ----
        floatx4 S[4];
        #pragma unroll
        for (int nt = 0; nt < 4; ++nt) {
            half8 kf0 = *(const half8*)(&Ks[(l15 + 16 * nt) * KS_STRIDE + quad * 8]);
            half8 kf1 = *(const half8*)(&Ks[(l15 + 16 * nt) * KS_STRIDE + 32 + quad * 8]);
            floatx4 s = {0.f, 0.f, 0.f, 0.f};
            s = __builtin_amdgcn_mfma_f32_16x16x32_f16(qfrag[0], kf0, s, 0, 0, 0);
            s = __builtin_amdgcn_mfma_f32_16x16x32_f16(qfrag[1], kf1, s, 0, 0, 0);
            S[nt] = s;
        }

        // ---- online softmax (base-2; rows = quad*4+r) ----
        float newm[4], alpha[4];
        #pragma unroll
        for (int r = 0; r < 4; ++r) {
            float rm = fmaxf(fmaxf(S[0][r], S[1][r]), fmaxf(S[2][r], S[3][r]));
            rm = fmaxf(rm, __shfl_xor(rm, 1));
            rm = fmaxf(rm, __shfl_xor(rm, 2));
            rm = fmaxf(rm, __shfl_xor(rm, 4));
            rm = fmaxf(rm, __shfl_xor(rm, 8));
            float nm = fmaxf(m_i[r], rm);
            alpha[r] = __builtin_amdgcn_exp2f(m_i[r] - nm);
            newm[r] = nm;
        }
        #pragma unroll
        for (int nt = 0; nt < 4; ++nt) {
            #pragma unroll
            for (int r = 0; r < 4; ++r) {
                float p = __builtin_amdgcn_exp2f(S[nt][r] - newm[r]);
                S[nt][r] = p;
                myP[(quad * 4 + r) * P_STRIDE + nt * 16 + l15] = (_Float16)p;
            }
        }
        #pragma unroll
        for (int r = 0; r < 4; ++r) {
            float rs = S[0][r] + S[1][r] + S[2][r] + S[3][r];
            rs += __shfl_xor(rs, 1);
            rs += __shfl_xor(rs, 2);
            rs += __shfl_xor(rs, 4);
            rs += __shfl_xor(rs, 8);
            l_i[r] = l_i[r] * alpha[r] + rs;
            m_i[r] = newm[r];
            acc[0][r] *= alpha[r];
            acc[1][r] *= alpha[r];
            acc[2][r] *= alpha[r];
            acc[3][r] *= alpha[r];
        }

        // ---- O += P · V  (P via LDS round-trip C-layout -> A-layout) ----
        #pragma unroll
        for (int c = 0; c < 2; ++c) {
            half8 pf = *(const half8*)(&myP[l15 * P_STRIDE + c * 32 + quad * 8]);
            #pragma unroll
            for (int nt = 0; nt < 4; ++nt) {
                const _Float16* vb = &Vt[(l15 + 16 * nt) * VT_STRIDE + c * 32 + quad * 8];
                half4 v0 = *(const half4*)(vb);
                half4 v1 = *(const half4*)(vb + 4);
                half8 vf = __builtin_shufflevector(v0, v1, 0, 1, 2, 3, 4, 5, 6, 7);
                acc[nt] = __builtin_amdgcn_mfma_f32_16x16x32_f16(pf, vf, acc[nt], 0, 0, 0);
            }
        }
        __syncthreads();
    }

    // ---- epilogue: O/l, then out = O*wp + bp ----
    float inv_l[4];
    #pragma unroll
    for (int r = 0; r < 4; ++r) inv_l[r] = 1.0f / l_i[r];
    const int orow0 = qtile * QTILE + wave * 16 + quad * 4;
    #pragma unroll
    for (int nt = 0; nt < 4; ++nt) {
        int ch = ch0 + nt * 16 + l15;
        float wpv = wp[ch], bpv = bp[ch];
        #pragma unroll
        for (int r = 0; r < 4; ++r) {
            float o = acc[nt][r] * inv_l[r];
            out[((size_t)b * HW + orow0 + r) * CCH + ch] = o * wpv + bpv;
        }
    }
}

extern "C" void kernel_launch(void* const* d_in, const int* in_sizes, int n_in,
                              void* d_out, int out_size, void* d_ws, size_t ws_size,
                              hipStream_t stream) {
    const float* q_in = (const float*)d_in[0];
    const float* k_in = (const float*)d_in[1];
    const float* v_in = (const float*)d_in[2];
    const float* wq = (const float*)d_in[3];
    const float* bq = (const float*)d_in[4];
    const float* wk = (const float*)d_in[5];
    const float* bk = (const float*)d_in[6];
    const float* wv = (const float*)d_in[7];
    const float* bv = (const float*)d_in[8];
    const float* wp = (const float*)d_in[9];
    const float* bp = (const float*)d_in[10];
    float* out = (float*)d_out;

    dim3 grid(HW / QTILE, 4 * NH);   // 32 q-tiles x 16 (b,h)
    spatial_attn_kernel<<<grid, 512, 0, stream>>>(
        q_in, k_in, v_in, wq, bq, wk, bk, wv, bv, wp, bp, out);
}